// Round 3
// baseline (806.735 us; speedup 1.0000x reference)
//
#include <hip/hip_runtime.h>

// Problem constants
#define BN    2400   // B*N
#define NG    4      // groups
#define PIN   32     // in_points
#define OP    32     // out_points
#define CGD   64     // per-group in channels
#define DGD   64     // per-group out channels
#define DIM   256

// DTYPE NOTES:
//  R1: inputs read as bf16 -> dense NaN  => inputs are fp32 (reference dtype).
//  R2: output written as bf16 -> absmax 6.89 (decorrelated at LN scale, and
//      upper half of the fp32-sized d_out stayed zero) => output is fp32 too.
//  R3: fp32 output. Internal ws buffers remain bf16 (2% threshold headroom).

typedef __attribute__((ext_vector_type(8))) short bf16x8;
typedef __attribute__((ext_vector_type(4))) float f32x4;

__device__ __forceinline__ float b2f(unsigned short u) {
    union { unsigned int i; float f; } v; v.i = ((unsigned int)u) << 16; return v.f;
}
__device__ __forceinline__ unsigned short f2b(float f) {
    union { float f; unsigned int i; } v; v.f = f;
    unsigned int x = v.i;
    return (unsigned short)((x + 0x7fffu + ((x >> 16) & 1u)) >> 16);  // RNE
}

// Block-wide mean/rsqrt(var) over values each thread contributes (sum s, sumsq q).
__device__ __forceinline__ void block_stats(float s, float q, float* sRed, int tid,
                                            float inv_n, float& mean, float& istd) {
    #pragma unroll
    for (int off = 32; off > 0; off >>= 1) {
        s += __shfl_down(s, off, 64);
        q += __shfl_down(q, off, 64);
    }
    if ((tid & 63) == 0) { sRed[(tid >> 6) * 2] = s; sRed[(tid >> 6) * 2 + 1] = q; }
    __syncthreads();
    if (tid == 0) {
        float ts = 0.f, tq = 0.f;
        for (int w = 0; w < 4; ++w) { ts += sRed[2 * w]; tq += sRed[2 * w + 1]; }
        float m = ts * inv_n;
        float var = tq * inv_n - m * m;
        sRed[8] = m; sRed[9] = rsqrtf(var + 1e-5f);
    }
    __syncthreads();
    mean = sRed[8]; istd = sRed[9];
}

// ---------------------------------------------------------------------------
// Generic NT GEMM: C(MxN) = A(MxK-rowmajor) * W(NxK-rowmajor)^T + bias
// A32/W32: operand is fp32 in global (converted to bf16 while staging to LDS);
//          otherwise bf16 (ws buffer).
// OUT_MODE 0: bf16 out (+fp32 bias). OUT_MODE 2: fp32 split-K partial to
//             C + blockIdx.z*M*N, no bias.
// Tile 64x64, 4 waves each own a 32x32 quadrant of 2x2 MFMA 16x16x32_bf16.
// ---------------------------------------------------------------------------
template<int OUT_MODE, int A32, int W32>
__global__ __launch_bounds__(256) void gemm_nt_kernel(
    const void* __restrict__ A_,
    const void* __restrict__ W_,
    const float* __restrict__ bias,
    void* __restrict__ Cout,
    int M, int N, int ldK, int kLen)
{
    __shared__ short sA[64][72];   // +8 bf16 pad -> 144B row stride
    __shared__ short sB[64][72];

    const int m0 = blockIdx.x * 64;
    const int n0 = blockIdx.y * 64;
    const int tid = threadIdx.x;
    const int lane = tid & 63;
    const int wave = tid >> 6;
    const int l16 = lane & 15;
    const int quad = lane >> 4;
    const int wr = (wave >> 1) * 32;
    const int wc = (wave & 1) * 32;

    // loader: each thread stages a 16-element contiguous chunk per matrix
    const int lr = tid >> 2;            // row 0..63
    const int lc = (tid & 3) * 16;      // col 0,16,32,48

    f32x4 acc[2][2] = {};

    const int kbase = blockIdx.z * kLen;
    for (int k0 = kbase; k0 < kbase + kLen; k0 += 64) {
        // ---- stage A ----
        {
            const int gr = m0 + lr;
            bf16x8 v0 = {}, v1 = {};
            if (gr < M) {
                if (A32) {
                    const float* ap = (const float*)A_ + (size_t)gr * ldK + k0 + lc;
                    float4 x0 = ((const float4*)ap)[0];
                    float4 x1 = ((const float4*)ap)[1];
                    float4 x2 = ((const float4*)ap)[2];
                    float4 x3 = ((const float4*)ap)[3];
                    v0[0]=(short)f2b(x0.x); v0[1]=(short)f2b(x0.y); v0[2]=(short)f2b(x0.z); v0[3]=(short)f2b(x0.w);
                    v0[4]=(short)f2b(x1.x); v0[5]=(short)f2b(x1.y); v0[6]=(short)f2b(x1.z); v0[7]=(short)f2b(x1.w);
                    v1[0]=(short)f2b(x2.x); v1[1]=(short)f2b(x2.y); v1[2]=(short)f2b(x2.z); v1[3]=(short)f2b(x2.w);
                    v1[4]=(short)f2b(x3.x); v1[5]=(short)f2b(x3.y); v1[6]=(short)f2b(x3.z); v1[7]=(short)f2b(x3.w);
                } else {
                    const unsigned short* ap = (const unsigned short*)A_ + (size_t)gr * ldK + k0 + lc;
                    v0 = ((const bf16x8*)ap)[0];
                    v1 = ((const bf16x8*)ap)[1];
                }
            }
            *(bf16x8*)(&sA[lr][lc])     = v0;
            *(bf16x8*)(&sA[lr][lc + 8]) = v1;
        }
        // ---- stage W (N always multiple of 64 -> no row guard) ----
        {
            bf16x8 v0, v1;
            if (W32) {
                const float* wp = (const float*)W_ + (size_t)(n0 + lr) * ldK + k0 + lc;
                float4 x0 = ((const float4*)wp)[0];
                float4 x1 = ((const float4*)wp)[1];
                float4 x2 = ((const float4*)wp)[2];
                float4 x3 = ((const float4*)wp)[3];
                v0[0]=(short)f2b(x0.x); v0[1]=(short)f2b(x0.y); v0[2]=(short)f2b(x0.z); v0[3]=(short)f2b(x0.w);
                v0[4]=(short)f2b(x1.x); v0[5]=(short)f2b(x1.y); v0[6]=(short)f2b(x1.z); v0[7]=(short)f2b(x1.w);
                v1[0]=(short)f2b(x2.x); v1[1]=(short)f2b(x2.y); v1[2]=(short)f2b(x2.z); v1[3]=(short)f2b(x2.w);
                v1[4]=(short)f2b(x3.x); v1[5]=(short)f2b(x3.y); v1[6]=(short)f2b(x3.z); v1[7]=(short)f2b(x3.w);
            } else {
                const unsigned short* wp = (const unsigned short*)W_ + (size_t)(n0 + lr) * ldK + k0 + lc;
                v0 = ((const bf16x8*)wp)[0];
                v1 = ((const bf16x8*)wp)[1];
            }
            *(bf16x8*)(&sB[lr][lc])     = v0;
            *(bf16x8*)(&sB[lr][lc + 8]) = v1;
        }
        __syncthreads();
        #pragma unroll
        for (int ks = 0; ks < 64; ks += 32) {
            bf16x8 a0 = *(const bf16x8*)(&sA[wr + l16][ks + quad * 8]);
            bf16x8 a1 = *(const bf16x8*)(&sA[wr + 16 + l16][ks + quad * 8]);
            bf16x8 b0 = *(const bf16x8*)(&sB[wc + l16][ks + quad * 8]);
            bf16x8 b1 = *(const bf16x8*)(&sB[wc + 16 + l16][ks + quad * 8]);
            acc[0][0] = __builtin_amdgcn_mfma_f32_16x16x32_bf16(a0, b0, acc[0][0], 0, 0, 0);
            acc[0][1] = __builtin_amdgcn_mfma_f32_16x16x32_bf16(a0, b1, acc[0][1], 0, 0, 0);
            acc[1][0] = __builtin_amdgcn_mfma_f32_16x16x32_bf16(a1, b0, acc[1][0], 0, 0, 0);
            acc[1][1] = __builtin_amdgcn_mfma_f32_16x16x32_bf16(a1, b1, acc[1][1], 0, 0, 0);
        }
        __syncthreads();
    }

    // epilogue: D layout col=lane&15, row=quad*4+reg [m89/m91]
    #pragma unroll
    for (int s = 0; s < 2; ++s) {
        #pragma unroll
        for (int u = 0; u < 2; ++u) {
            const int col = n0 + wc + u * 16 + l16;
            const float bv = bias ? bias[col] : 0.0f;
            #pragma unroll
            for (int r = 0; r < 4; ++r) {
                const int row = m0 + wr + s * 16 + quad * 4 + r;
                if (row < M) {
                    const float val = acc[s][u][r] + bv;
                    if (OUT_MODE == 0) {
                        ((unsigned short*)Cout)[(size_t)row * N + col] = f2b(val);
                    } else {
                        float* o = (float*)Cout + (size_t)blockIdx.z * M * N;
                        o[(size_t)row * N + col] = val;
                    }
                }
            }
        }
    }
}

// ---------------------------------------------------------------------------
// Phase 2, reg branch: per (t,g): fMS = relu(LN2d(S @ relu(LN2d(f @ M))))
// ---------------------------------------------------------------------------
__global__ __launch_bounds__(256) void p2_reg_kernel(
    const float* __restrict__ feats,           // (BN,G,32,64) fp32
    const unsigned short* __restrict__ YM,     // (BN,16384) bf16: g*4096+c*64+d
    const unsigned short* __restrict__ YS,     // (BN,4096)  bf16: g*1024+o*32+p
    unsigned short* __restrict__ FMS)          // (BN,8192)  bf16: g*2048+o*64+d
{
    const int t = blockIdx.x, g = blockIdx.y;
    const int tid = threadIdx.x;

    __shared__ float sf[32][68];
    __shared__ float sM[64][64];
    __shared__ float sT[32][68];
    __shared__ float sS[32][36];
    __shared__ float sRed[16];

    {   // f: 2048 fp32 elems, 8/thread
        const float* fp = feats + (size_t)(t * NG + g) * (PIN * CGD) + tid * 8;
        float4 x0 = ((const float4*)fp)[0];
        float4 x1 = ((const float4*)fp)[1];
        const int p = tid >> 3, c0 = (tid & 7) * 8;
        sf[p][c0+0]=x0.x; sf[p][c0+1]=x0.y; sf[p][c0+2]=x0.z; sf[p][c0+3]=x0.w;
        sf[p][c0+4]=x1.x; sf[p][c0+5]=x1.y; sf[p][c0+6]=x1.z; sf[p][c0+7]=x1.w;
    }
    {   // M: 4096 bf16 elems, 16/thread
        const unsigned short* mp = YM + (size_t)t * 16384 + g * 4096;
        #pragma unroll
        for (int h = 0; h < 2; ++h) {
            const int e = tid * 16 + h * 8;
            bf16x8 v = *(const bf16x8*)(mp + e);
            const int c = e >> 6, d0 = e & 63;
            #pragma unroll
            for (int j = 0; j < 8; ++j) sM[c][d0 + j] = b2f((unsigned short)v[j]);
        }
    }
    {   // S: 1024 bf16 elems, 4/thread
        const unsigned short* sp = YS + (size_t)t * 4096 + g * 1024;
        const int e = tid * 4, o = e >> 5, p0 = e & 31;
        #pragma unroll
        for (int j = 0; j < 4; ++j) sS[o][p0 + j] = b2f(sp[e + j]);
    }
    __syncthreads();

    const int p = tid >> 3;
    const int db = (tid & 7) * 8;

    float acc[8] = {};
    for (int c = 0; c < 64; ++c) {
        const float fv = sf[p][c];
        #pragma unroll
        for (int j = 0; j < 8; ++j) acc[j] += fv * sM[c][db + j];
    }
    float ls = 0.f, lq = 0.f;
    #pragma unroll
    for (int j = 0; j < 8; ++j) { ls += acc[j]; lq += acc[j] * acc[j]; }
    float mean, istd;
    block_stats(ls, lq, sRed, tid, 1.0f / 2048.0f, mean, istd);
    #pragma unroll
    for (int j = 0; j < 8; ++j) {
        const float y = (acc[j] - mean) * istd;
        sT[p][db + j] = y > 0.f ? y : 0.f;
    }
    __syncthreads();

    float acc2[8] = {};
    for (int pp = 0; pp < 32; ++pp) {
        const float sv = sS[p][pp];
        #pragma unroll
        for (int j = 0; j < 8; ++j) acc2[j] += sv * sT[pp][db + j];
    }
    ls = 0.f; lq = 0.f;
    #pragma unroll
    for (int j = 0; j < 8; ++j) { ls += acc2[j]; lq += acc2[j] * acc2[j]; }
    block_stats(ls, lq, sRed, tid, 1.0f / 2048.0f, mean, istd);

    bf16x8 st;
    #pragma unroll
    for (int j = 0; j < 8; ++j) {
        float y = (acc2[j] - mean) * istd;
        y = y > 0.f ? y : 0.f;
        st[j] = (short)f2b(y);
    }
    *(bf16x8*)(FMS + (size_t)t * 8192 + g * 2048 + p * 64 + db) = st;
}

// ---------------------------------------------------------------------------
// Phase 2, cls branch: v = relu(LN2d(f@vW)); k = v·kw^T + kb;
// sc = softmax(q@k/8); fc = relu(LN2d(sc@v))
// ---------------------------------------------------------------------------
__global__ __launch_bounds__(256) void p2_cls_kernel(
    const float* __restrict__ feats,
    const unsigned short* __restrict__ YV,     // (BN,16384) bf16
    const unsigned short* __restrict__ YQ,     // (BN,4096) bf16: g*1024+o*32+i
    const float* __restrict__ kwp,             // (128,64) fp32: (g*32+i)*64+d
    const float* __restrict__ kbp,             // (128) fp32
    unsigned short* __restrict__ FC)
{
    const int t = blockIdx.x, g = blockIdx.y;
    const int tid = threadIdx.x;

    __shared__ float sf[32][68];
    __shared__ float sM[64][64];
    __shared__ float sT[32][68];    // v
    __shared__ float sK[32][65];    // kw[i][d]
    __shared__ float sKP[32][33];   // k[i][p]
    __shared__ float sQ[32][33];
    __shared__ float sSC[32][33];
    __shared__ float sKB[32];
    __shared__ float sRed[16];

    {
        const float* fp = feats + (size_t)(t * NG + g) * (PIN * CGD) + tid * 8;
        float4 x0 = ((const float4*)fp)[0];
        float4 x1 = ((const float4*)fp)[1];
        const int p = tid >> 3, c0 = (tid & 7) * 8;
        sf[p][c0+0]=x0.x; sf[p][c0+1]=x0.y; sf[p][c0+2]=x0.z; sf[p][c0+3]=x0.w;
        sf[p][c0+4]=x1.x; sf[p][c0+5]=x1.y; sf[p][c0+6]=x1.z; sf[p][c0+7]=x1.w;
    }
    {
        const unsigned short* mp = YV + (size_t)t * 16384 + g * 4096;
        #pragma unroll
        for (int h = 0; h < 2; ++h) {
            const int e = tid * 16 + h * 8;
            bf16x8 v = *(const bf16x8*)(mp + e);
            const int c = e >> 6, d0 = e & 63;
            #pragma unroll
            for (int j = 0; j < 8; ++j) sM[c][d0 + j] = b2f((unsigned short)v[j]);
        }
    }
    {   // kw: 2048 fp32 elems, 8/thread
        const float* kp = kwp + (size_t)g * 32 * 64 + tid * 8;
        float4 x0 = ((const float4*)kp)[0];
        float4 x1 = ((const float4*)kp)[1];
        const int i = tid >> 3, d0 = (tid & 7) * 8;
        sK[i][d0+0]=x0.x; sK[i][d0+1]=x0.y; sK[i][d0+2]=x0.z; sK[i][d0+3]=x0.w;
        sK[i][d0+4]=x1.x; sK[i][d0+5]=x1.y; sK[i][d0+6]=x1.z; sK[i][d0+7]=x1.w;
    }
    {   // q: 1024 bf16 elems, 4/thread
        const unsigned short* qp = YQ + (size_t)t * 4096 + g * 1024;
        const int e = tid * 4, o = e >> 5, i0 = e & 31;
        #pragma unroll
        for (int j = 0; j < 4; ++j) sQ[o][i0 + j] = b2f(qp[e + j]);
    }
    if (tid < 32) sKB[tid] = kbp[g * 32 + tid];
    __syncthreads();

    const int p = tid >> 3;
    const int db = (tid & 7) * 8;

    // v = relu(LN2d(f @ vW))
    float acc[8] = {};
    for (int c = 0; c < 64; ++c) {
        const float fv = sf[p][c];
        #pragma unroll
        for (int j = 0; j < 8; ++j) acc[j] += fv * sM[c][db + j];
    }
    float ls = 0.f, lq = 0.f;
    #pragma unroll
    for (int j = 0; j < 8; ++j) { ls += acc[j]; lq += acc[j] * acc[j]; }
    float mean, istd;
    block_stats(ls, lq, sRed, tid, 1.0f / 2048.0f, mean, istd);
    #pragma unroll
    for (int j = 0; j < 8; ++j) {
        const float y = (acc[j] - mean) * istd;
        sT[p][db + j] = y > 0.f ? y : 0.f;
    }
    __syncthreads();

    {   // k[i][p] = sum_d v[p][d]*kw[i][d] + kb[i]
        const int ib = (tid & 7) * 4;
        float a4[4] = {};
        for (int d = 0; d < 64; ++d) {
            const float tv = sT[p][d];
            #pragma unroll
            for (int j = 0; j < 4; ++j) a4[j] += tv * sK[ib + j][d];
        }
        #pragma unroll
        for (int j = 0; j < 4; ++j) sKP[ib + j][p] = a4[j] + sKB[ib + j];
    }
    __syncthreads();

    {   // logits + softmax over p (rows owned by groups of 8 lanes)
        const int o = tid >> 3;
        const int pb = (tid & 7) * 4;
        float a4[4] = {};
        for (int i = 0; i < 32; ++i) {
            const float qq = sQ[o][i];
            #pragma unroll
            for (int j = 0; j < 4; ++j) a4[j] += qq * sKP[i][pb + j];
        }
        #pragma unroll
        for (int j = 0; j < 4; ++j) a4[j] *= 0.125f;  // /sqrt(64)
        float mx = fmaxf(fmaxf(a4[0], a4[1]), fmaxf(a4[2], a4[3]));
        #pragma unroll
        for (int m = 1; m < 8; m <<= 1) mx = fmaxf(mx, __shfl_xor(mx, m, 64));
        float sum = 0.f;
        #pragma unroll
        for (int j = 0; j < 4; ++j) { a4[j] = expf(a4[j] - mx); sum += a4[j]; }
        #pragma unroll
        for (int m = 1; m < 8; m <<= 1) sum += __shfl_xor(sum, m, 64);
        const float inv_s = 1.0f / sum;
        #pragma unroll
        for (int j = 0; j < 4; ++j) sSC[o][pb + j] = a4[j] * inv_s;
    }
    __syncthreads();

    // fc = relu(LN2d(sc @ v))
    float acc2[8] = {};
    for (int pp = 0; pp < 32; ++pp) {
        const float sv = sSC[p][pp];
        #pragma unroll
        for (int j = 0; j < 8; ++j) acc2[j] += sv * sT[pp][db + j];
    }
    ls = 0.f; lq = 0.f;
    #pragma unroll
    for (int j = 0; j < 8; ++j) { ls += acc2[j]; lq += acc2[j] * acc2[j]; }
    block_stats(ls, lq, sRed, tid, 1.0f / 2048.0f, mean, istd);

    bf16x8 st;
    #pragma unroll
    for (int j = 0; j < 8; ++j) {
        float y = (acc2[j] - mean) * istd;
        y = y > 0.f ? y : 0.f;
        st[j] = (short)f2b(y);
    }
    *(bf16x8*)(FC + (size_t)t * 8192 + g * 2048 + p * 64 + db) = st;
}

// ---------------------------------------------------------------------------
// Final: reduce split-K partials, residual add, affine LN over 256, fp32 out.
// blockIdx.y: 0 = reg branch, 1 = cls branch.
// ---------------------------------------------------------------------------
__global__ __launch_bounds__(256) void final_ln_kernel(
    const float* __restrict__ qv,
    const float* __restrict__ MSP,   // (8, BN, 256) fp32 partials
    const float* __restrict__ CLP,
    const float* __restrict__ Wv_b,
    const float* __restrict__ Wv2_b,
    const float* __restrict__ lnA_w,
    const float* __restrict__ lnA_b,
    const float* __restrict__ lnB_w,
    const float* __restrict__ lnB_b,
    float* __restrict__ out)
{
    __shared__ float sRed[16];
    const int t = blockIdx.x;
    const int br = blockIdx.y;
    const int c = threadIdx.x;
    const float* P = br ? CLP : MSP;
    const float* bias = br ? Wv2_b : Wv_b;
    const float* lw = br ? lnB_w : lnA_w;
    const float* lb = br ? lnB_b : lnA_b;

    float x = qv[t * 256 + c] + bias[c];
    #pragma unroll
    for (int s = 0; s < 8; ++s) x += P[(size_t)s * (BN * 256) + t * 256 + c];

    float mean, istd;
    block_stats(x, x * x, sRed, c, 1.0f / 256.0f, mean, istd);
    const float y = (x - mean) * istd * lw[c] + lb[c];
    out[(size_t)br * (BN * 256) + t * 256 + c] = y;
}

// ---------------------------------------------------------------------------
extern "C" void kernel_launch(void* const* d_in, const int* in_sizes, int n_in,
                              void* d_out, int out_size, void* d_ws, size_t ws_size,
                              hipStream_t stream) {
    const float* feats = (const float*)d_in[0];
    const float* qv    = (const float*)d_in[1];
    // d_in[2..6]: sample_points_xy / offset / sample_points_z / scale_logit / query_box — unused
    const float* m_w   = (const float*)d_in[7];
    const float* m_b   = (const float*)d_in[8];
    const float* s_w   = (const float*)d_in[9];
    const float* s_b   = (const float*)d_in[10];
    const float* q_w   = (const float*)d_in[11];
    const float* q_b   = (const float*)d_in[12];
    const float* v_w   = (const float*)d_in[13];
    const float* v_b   = (const float*)d_in[14];
    const float* k_w   = (const float*)d_in[15];
    const float* k_b   = (const float*)d_in[16];
    const float* Wv_w  = (const float*)d_in[17];
    const float* Wv_b  = (const float*)d_in[18];
    const float* Wv2_w = (const float*)d_in[19];
    const float* Wv2_b = (const float*)d_in[20];
    const float* lnA_w = (const float*)d_in[21];
    const float* lnA_b = (const float*)d_in[22];
    const float* lnB_w = (const float*)d_in[23];
    const float* lnB_b = (const float*)d_in[24];

    char* ws = (char*)d_ws;
    // Workspace schedule (177 MB peak); YM region reused:
    //   [gen M,S] -> p2_reg -> [gen V,Q over M,S] -> p2_cls -> [MSP/CLP over V,Q]
    const size_t OFF_YM  = 0;                         // 2400*16384*2 = 78,643,200
    const size_t OFF_YS  = 78643200;                  // 2400* 4096*2 = 19,660,800
    const size_t OFF_FMS = 98304000;                  // 2400* 8192*2 = 39,321,600
    const size_t OFF_FC  = 137625600;                 // 39,321,600 (ends 176,947,200)
    const size_t OFF_MSP = 0;                         // 8*2400*256*4 = 19,660,800 (YM dead)
    const size_t OFF_CLP = 19660800;

    unsigned short* YM  = (unsigned short*)(ws + OFF_YM);
    unsigned short* YS  = (unsigned short*)(ws + OFF_YS);
    unsigned short* FMS = (unsigned short*)(ws + OFF_FMS);
    unsigned short* FC  = (unsigned short*)(ws + OFF_FC);
    float* MSP = (float*)(ws + OFF_MSP);
    float* CLP = (float*)(ws + OFF_CLP);

    const dim3 blk(256);
    // reg branch: generators (fp32 A, fp32 W -> bf16 ws out)
    gemm_nt_kernel<0,1,1><<<dim3(38, 256, 1), blk, 0, stream>>>(qv, m_w, m_b, YM, BN, 16384, 256, 256);
    gemm_nt_kernel<0,1,1><<<dim3(38, 64, 1),  blk, 0, stream>>>(qv, s_w, s_b, YS, BN, 4096, 256, 256);
    p2_reg_kernel<<<dim3(BN, NG), blk, 0, stream>>>(feats, YM, YS, FMS);
    // cls branch (reuse YM/YS regions)
    gemm_nt_kernel<0,1,1><<<dim3(38, 256, 1), blk, 0, stream>>>(qv, v_w, v_b, YM, BN, 16384, 256, 256);
    gemm_nt_kernel<0,1,1><<<dim3(38, 64, 1),  blk, 0, stream>>>(qv, q_w, q_b, YS, BN, 4096, 256, 256);
    p2_cls_kernel<<<dim3(BN, NG), blk, 0, stream>>>(feats, YM, YS, k_w, k_b, FC);
    // output projections: bf16 ws A, fp32 W, split-K=8 fp32 partials
    gemm_nt_kernel<2,0,1><<<dim3(38, 4, 8), blk, 0, stream>>>(FMS, Wv_w,  nullptr, MSP, BN, 256, 8192, 1024);
    gemm_nt_kernel<2,0,1><<<dim3(38, 4, 8), blk, 0, stream>>>(FC,  Wv2_w, nullptr, CLP, BN, 256, 8192, 1024);
    final_ln_kernel<<<dim3(BN, 2), blk, 0, stream>>>(qv, MSP, CLP, Wv_b, Wv2_b,
                                                     lnA_w, lnA_b, lnB_w, lnB_b,
                                                     (float*)d_out);
}

// Round 4
// 544.631 us; speedup vs baseline: 1.4812x; 1.4812x over previous
//
#include <hip/hip_runtime.h>

// Problem constants
#define BN    2400   // B*N
#define NG    4      // groups
#define PIN   32     // in_points
#define OP    32     // out_points
#define CGD   64     // per-group in channels
#define DGD   64     // per-group out channels
#define DIM   256

// DTYPE: inputs fp32, output fp32 (R1/R2 bisection). Internal ws bf16.
// R4: phase-2 kernels MFMA-ized. Generator weights pre-permuted (g,c,d)->(g,d,c)
// and pre-converted to bf16 so YM/YV arrive in [d][c] order (B-operand-ready,
// no LDS transpose needed).

typedef __attribute__((ext_vector_type(8))) short bf16x8;
typedef __attribute__((ext_vector_type(4))) short bf16x4;
typedef __attribute__((ext_vector_type(4))) float f32x4;

__device__ __forceinline__ float b2f(unsigned short u) {
    union { unsigned int i; float f; } v; v.i = ((unsigned int)u) << 16; return v.f;
}
__device__ __forceinline__ unsigned short f2b(float f) {
    union { float f; unsigned int i; } v; v.f = f;
    unsigned int x = v.i;
    return (unsigned short)((x + 0x7fffu + ((x >> 16) & 1u)) >> 16);  // RNE
}

// Block-wide mean/rsqrt(var) over values each thread contributes (sum s, sumsq q).
__device__ __forceinline__ void block_stats(float s, float q, float* sRed, int tid,
                                            float inv_n, float& mean, float& istd) {
    #pragma unroll
    for (int off = 32; off > 0; off >>= 1) {
        s += __shfl_down(s, off, 64);
        q += __shfl_down(q, off, 64);
    }
    if ((tid & 63) == 0) { sRed[(tid >> 6) * 2] = s; sRed[(tid >> 6) * 2 + 1] = q; }
    __syncthreads();
    if (tid == 0) {
        float ts = 0.f, tq = 0.f;
        for (int w = 0; w < 4; ++w) { ts += sRed[2 * w]; tq += sRed[2 * w + 1]; }
        float m = ts * inv_n;
        float var = tq * inv_n - m * m;
        sRed[8] = m; sRed[9] = rsqrtf(var + 1e-5f);
    }
    __syncthreads();
    mean = sRed[8]; istd = sRed[9];
}

// ---------------------------------------------------------------------------
// Weight prep: fp32 -> bf16, optional row permutation (g,c,d)->(g,d,c), plus
// bias permutation. Block = 256 threads = 4 rows x 64 lanes (float4 each).
// ---------------------------------------------------------------------------
template<int PERM>
__global__ __launch_bounds__(256) void prep_w_kernel(
    const float* __restrict__ w, const float* __restrict__ b,
    unsigned short* __restrict__ wOut, float* __restrict__ bOut)
{
    const int row_o = blockIdx.x * 4 + (threadIdx.x >> 6);
    const int lane = threadIdx.x & 63;
    int row_i;
    if (PERM) {
        const int g = row_o >> 12, d = (row_o >> 6) & 63, c = row_o & 63;
        row_i = (g << 12) + c * 64 + d;
    } else {
        row_i = row_o;
    }
    const float4 x = *(const float4*)(w + (size_t)row_i * 256 + lane * 4);
    bf16x4 pk;
    pk[0] = (short)f2b(x.x); pk[1] = (short)f2b(x.y);
    pk[2] = (short)f2b(x.z); pk[3] = (short)f2b(x.w);
    *(bf16x4*)(wOut + (size_t)row_o * 256 + lane * 4) = pk;
    if (PERM && bOut && lane == 0) bOut[row_o] = b[row_i];
}

// ---------------------------------------------------------------------------
// Generic NT GEMM: C(MxN) = A(MxK-rowmajor) * W(NxK-rowmajor)^T + bias
// A32/W32: fp32-in-global (convert while staging) vs bf16.
// OUT_MODE 0: bf16 out. OUT_MODE 2: fp32 split-K partial (blockIdx.z), no bias.
// Tile 64x64, 4 waves x (2x2) MFMA 16x16x32_bf16.
// ---------------------------------------------------------------------------
template<int OUT_MODE, int A32, int W32>
__global__ __launch_bounds__(256) void gemm_nt_kernel(
    const void* __restrict__ A_,
    const void* __restrict__ W_,
    const float* __restrict__ bias,
    void* __restrict__ Cout,
    int M, int N, int ldK, int kLen)
{
    __shared__ short sA[64][72];
    __shared__ short sB[64][72];

    const int m0 = blockIdx.x * 64;
    const int n0 = blockIdx.y * 64;
    const int tid = threadIdx.x;
    const int lane = tid & 63;
    const int wave = tid >> 6;
    const int l16 = lane & 15;
    const int quad = lane >> 4;
    const int wr = (wave >> 1) * 32;
    const int wc = (wave & 1) * 32;

    const int lr = tid >> 2;            // row 0..63
    const int lc = (tid & 3) * 16;      // col 0,16,32,48

    f32x4 acc[2][2] = {};

    const int kbase = blockIdx.z * kLen;
    for (int k0 = kbase; k0 < kbase + kLen; k0 += 64) {
        {   // stage A
            const int gr = m0 + lr;
            bf16x8 v0 = {}, v1 = {};
            if (gr < M) {
                if (A32) {
                    const float* ap = (const float*)A_ + (size_t)gr * ldK + k0 + lc;
                    float4 x0 = ((const float4*)ap)[0];
                    float4 x1 = ((const float4*)ap)[1];
                    float4 x2 = ((const float4*)ap)[2];
                    float4 x3 = ((const float4*)ap)[3];
                    v0[0]=(short)f2b(x0.x); v0[1]=(short)f2b(x0.y); v0[2]=(short)f2b(x0.z); v0[3]=(short)f2b(x0.w);
                    v0[4]=(short)f2b(x1.x); v0[5]=(short)f2b(x1.y); v0[6]=(short)f2b(x1.z); v0[7]=(short)f2b(x1.w);
                    v1[0]=(short)f2b(x2.x); v1[1]=(short)f2b(x2.y); v1[2]=(short)f2b(x2.z); v1[3]=(short)f2b(x2.w);
                    v1[4]=(short)f2b(x3.x); v1[5]=(short)f2b(x3.y); v1[6]=(short)f2b(x3.z); v1[7]=(short)f2b(x3.w);
                } else {
                    const unsigned short* ap = (const unsigned short*)A_ + (size_t)gr * ldK + k0 + lc;
                    v0 = ((const bf16x8*)ap)[0];
                    v1 = ((const bf16x8*)ap)[1];
                }
            }
            *(bf16x8*)(&sA[lr][lc])     = v0;
            *(bf16x8*)(&sA[lr][lc + 8]) = v1;
        }
        {   // stage W (N multiple of 64)
            bf16x8 v0, v1;
            if (W32) {
                const float* wp = (const float*)W_ + (size_t)(n0 + lr) * ldK + k0 + lc;
                float4 x0 = ((const float4*)wp)[0];
                float4 x1 = ((const float4*)wp)[1];
                float4 x2 = ((const float4*)wp)[2];
                float4 x3 = ((const float4*)wp)[3];
                v0[0]=(short)f2b(x0.x); v0[1]=(short)f2b(x0.y); v0[2]=(short)f2b(x0.z); v0[3]=(short)f2b(x0.w);
                v0[4]=(short)f2b(x1.x); v0[5]=(short)f2b(x1.y); v0[6]=(short)f2b(x1.z); v0[7]=(short)f2b(x1.w);
                v1[0]=(short)f2b(x2.x); v1[1]=(short)f2b(x2.y); v1[2]=(short)f2b(x2.z); v1[3]=(short)f2b(x2.w);
                v1[4]=(short)f2b(x3.x); v1[5]=(short)f2b(x3.y); v1[6]=(short)f2b(x3.z); v1[7]=(short)f2b(x3.w);
            } else {
                const unsigned short* wp = (const unsigned short*)W_ + (size_t)(n0 + lr) * ldK + k0 + lc;
                v0 = ((const bf16x8*)wp)[0];
                v1 = ((const bf16x8*)wp)[1];
            }
            *(bf16x8*)(&sB[lr][lc])     = v0;
            *(bf16x8*)(&sB[lr][lc + 8]) = v1;
        }
        __syncthreads();
        #pragma unroll
        for (int ks = 0; ks < 64; ks += 32) {
            bf16x8 a0 = *(const bf16x8*)(&sA[wr + l16][ks + quad * 8]);
            bf16x8 a1 = *(const bf16x8*)(&sA[wr + 16 + l16][ks + quad * 8]);
            bf16x8 b0 = *(const bf16x8*)(&sB[wc + l16][ks + quad * 8]);
            bf16x8 b1 = *(const bf16x8*)(&sB[wc + 16 + l16][ks + quad * 8]);
            acc[0][0] = __builtin_amdgcn_mfma_f32_16x16x32_bf16(a0, b0, acc[0][0], 0, 0, 0);
            acc[0][1] = __builtin_amdgcn_mfma_f32_16x16x32_bf16(a0, b1, acc[0][1], 0, 0, 0);
            acc[1][0] = __builtin_amdgcn_mfma_f32_16x16x32_bf16(a1, b0, acc[1][0], 0, 0, 0);
            acc[1][1] = __builtin_amdgcn_mfma_f32_16x16x32_bf16(a1, b1, acc[1][1], 0, 0, 0);
        }
        __syncthreads();
    }

    #pragma unroll
    for (int s = 0; s < 2; ++s) {
        #pragma unroll
        for (int u = 0; u < 2; ++u) {
            const int col = n0 + wc + u * 16 + l16;
            const float bv = bias ? bias[col] : 0.0f;
            #pragma unroll
            for (int r = 0; r < 4; ++r) {
                const int row = m0 + wr + s * 16 + quad * 4 + r;
                if (row < M) {
                    const float val = acc[s][u][r] + bv;
                    if (OUT_MODE == 0) {
                        ((unsigned short*)Cout)[(size_t)row * N + col] = f2b(val);
                    } else {
                        float* o = (float*)Cout + (size_t)blockIdx.z * M * N;
                        o[(size_t)row * N + col] = val;
                    }
                }
            }
        }
    }
}

// ---------------------------------------------------------------------------
// Phase 2 reg (MFMA): per (t,g): fMS = relu(LN2d(S @ relu(LN2d(f @ M))))
// YM arrives as [t][g][d][c] (weights pre-permuted) -> direct B-operand.
// 4 waves; stage A: wave=d-tile(4), mt=0..1, K=64; stage B: same, K=32.
// ---------------------------------------------------------------------------
__global__ __launch_bounds__(256) void p2_reg_kernel(
    const float* __restrict__ feats,           // (BN,G,32,64) fp32
    const unsigned short* __restrict__ YM,     // (BN,16384) bf16: g*4096 + d*64 + c
    const unsigned short* __restrict__ YS,     // (BN,4096)  bf16: g*1024 + o*32 + p
    unsigned short* __restrict__ FMS)          // (BN,8192)  bf16: g*2048 + o*64 + d
{
    const int t = blockIdx.x, g = blockIdx.y;
    const int tid = threadIdx.x;
    const int wave = tid >> 6, lane = tid & 63;
    const int l16 = lane & 15, quad = lane >> 4;

    __shared__ short fB[32][72];    // f as bf16 [p][c]
    __shared__ short Mt[64][72];    // M^T [d][c]
    __shared__ short sS[32][40];    // S [o][p]
    __shared__ short X1T[64][40];   // relu(LN(f@M))^T [d][p]
    __shared__ float sRed[16];

    {   // f: 2048 fp32 -> bf16
        const float* fp = feats + (size_t)(t * NG + g) * 2048 + tid * 8;
        float4 x0 = ((const float4*)fp)[0];
        float4 x1 = ((const float4*)fp)[1];
        bf16x8 v;
        v[0]=(short)f2b(x0.x); v[1]=(short)f2b(x0.y); v[2]=(short)f2b(x0.z); v[3]=(short)f2b(x0.w);
        v[4]=(short)f2b(x1.x); v[5]=(short)f2b(x1.y); v[6]=(short)f2b(x1.z); v[7]=(short)f2b(x1.w);
        *(bf16x8*)(&fB[tid >> 3][(tid & 7) * 8]) = v;
    }
    {   // Mt: 4096 bf16, already [d][c]
        const unsigned short* mp = YM + (size_t)t * 16384 + g * 4096 + tid * 16;
        bf16x8 v0 = ((const bf16x8*)mp)[0];
        bf16x8 v1 = ((const bf16x8*)mp)[1];
        const int d = tid >> 2, c0 = (tid & 3) * 16;
        *(bf16x8*)(&Mt[d][c0])     = v0;
        *(bf16x8*)(&Mt[d][c0 + 8]) = v1;
    }
    {   // S: 1024 bf16
        const unsigned short* sp = YS + (size_t)t * 4096 + g * 1024 + tid * 4;
        *(bf16x4*)(&sS[tid >> 3][(tid & 7) * 4]) = *(const bf16x4*)sp;
    }
    __syncthreads();

    // Stage A: X1[p][d] = f @ M. wave = d-tile, mt = p-tile.
    f32x4 accA[2] = {};
    #pragma unroll
    for (int ks = 0; ks < 64; ks += 32) {
        bf16x8 b = *(const bf16x8*)(&Mt[wave * 16 + l16][ks + quad * 8]);
        #pragma unroll
        for (int mt = 0; mt < 2; ++mt) {
            bf16x8 a = *(const bf16x8*)(&fB[mt * 16 + l16][ks + quad * 8]);
            accA[mt] = __builtin_amdgcn_mfma_f32_16x16x32_bf16(a, b, accA[mt], 0, 0, 0);
        }
    }
    float ls = 0.f, lq = 0.f;
    #pragma unroll
    for (int mt = 0; mt < 2; ++mt)
        #pragma unroll
        for (int r = 0; r < 4; ++r) { float v = accA[mt][r]; ls += v; lq += v * v; }
    float mean, istd;
    block_stats(ls, lq, sRed, tid, 1.0f / 2048.0f, mean, istd);
    #pragma unroll
    for (int mt = 0; mt < 2; ++mt) {
        bf16x4 pk;
        #pragma unroll
        for (int r = 0; r < 4; ++r) {
            float y = (accA[mt][r] - mean) * istd;
            pk[r] = (short)f2b(y > 0.f ? y : 0.f);
        }
        // D: row p = mt*16+quad*4+r, col d = wave*16+l16 -> X1T[d][p]
        *(bf16x4*)(&X1T[wave * 16 + l16][mt * 16 + quad * 4]) = pk;
    }
    __syncthreads();

    // Stage B: X2[o][d] = S @ X1. wave = d-tile, K = 32 (p).
    f32x4 accB[2] = {};
    {
        bf16x8 b = *(const bf16x8*)(&X1T[wave * 16 + l16][quad * 8]);
        #pragma unroll
        for (int mt = 0; mt < 2; ++mt) {
            bf16x8 a = *(const bf16x8*)(&sS[mt * 16 + l16][quad * 8]);
            accB[mt] = __builtin_amdgcn_mfma_f32_16x16x32_bf16(a, b, accB[mt], 0, 0, 0);
        }
    }
    ls = 0.f; lq = 0.f;
    #pragma unroll
    for (int mt = 0; mt < 2; ++mt)
        #pragma unroll
        for (int r = 0; r < 4; ++r) { float v = accB[mt][r]; ls += v; lq += v * v; }
    block_stats(ls, lq, sRed, tid, 1.0f / 2048.0f, mean, istd);

    unsigned short* outp = FMS + (size_t)t * 8192 + g * 2048;
    const int d = wave * 16 + l16;
    #pragma unroll
    for (int mt = 0; mt < 2; ++mt)
        #pragma unroll
        for (int r = 0; r < 4; ++r) {
            float y = (accB[mt][r] - mean) * istd;
            outp[(mt * 16 + quad * 4 + r) * 64 + d] = f2b(y > 0.f ? y : 0.f);
        }
}

// ---------------------------------------------------------------------------
// Phase 2 cls (MFMA): v = relu(LN2d(f@vW)); k = kw·v^T + kb;
// sc = softmax(q@k/8); fc = relu(LN2d(sc@v))
// ---------------------------------------------------------------------------
__global__ __launch_bounds__(256) void p2_cls_kernel(
    const float* __restrict__ feats,
    const unsigned short* __restrict__ YV,     // (BN,16384) bf16 [g][d][c]
    const unsigned short* __restrict__ YQ,     // (BN,4096)  bf16 [g][o][i]
    const float* __restrict__ kwp,             // (128,64) fp32: (g*32+i)*64+d
    const float* __restrict__ kbp,             // (128) fp32
    unsigned short* __restrict__ FC)
{
    const int t = blockIdx.x, g = blockIdx.y;
    const int tid = threadIdx.x;
    const int wave = tid >> 6, lane = tid & 63;
    const int l16 = lane & 15, quad = lane >> 4;

    __shared__ short fB[32][72];    // f [p][c]
    __shared__ short Vt[64][72];    // vW^T [d][c]
    __shared__ short kw[32][72];    // kw [i][d]
    __shared__ short vRM[32][72];   // v [p][d]
    __shared__ short vT[64][40];    // v^T [d][p]
    __shared__ short kT[32][40];    // k^T [p][i]
    __shared__ short sQ[32][40];    // q [o][i]
    __shared__ short sSC[32][40];   // sc [o][p]
    __shared__ float sKB[32];
    __shared__ float sRed[16];

    {   // f
        const float* fp = feats + (size_t)(t * NG + g) * 2048 + tid * 8;
        float4 x0 = ((const float4*)fp)[0];
        float4 x1 = ((const float4*)fp)[1];
        bf16x8 v;
        v[0]=(short)f2b(x0.x); v[1]=(short)f2b(x0.y); v[2]=(short)f2b(x0.z); v[3]=(short)f2b(x0.w);
        v[4]=(short)f2b(x1.x); v[5]=(short)f2b(x1.y); v[6]=(short)f2b(x1.z); v[7]=(short)f2b(x1.w);
        *(bf16x8*)(&fB[tid >> 3][(tid & 7) * 8]) = v;
    }
    {   // Vt
        const unsigned short* mp = YV + (size_t)t * 16384 + g * 4096 + tid * 16;
        bf16x8 v0 = ((const bf16x8*)mp)[0];
        bf16x8 v1 = ((const bf16x8*)mp)[1];
        const int d = tid >> 2, c0 = (tid & 3) * 16;
        *(bf16x8*)(&Vt[d][c0])     = v0;
        *(bf16x8*)(&Vt[d][c0 + 8]) = v1;
    }
    {   // kw fp32 -> bf16 [i][d]
        const float* kp = kwp + (size_t)g * 2048 + tid * 8;
        float4 x0 = ((const float4*)kp)[0];
        float4 x1 = ((const float4*)kp)[1];
        bf16x8 v;
        v[0]=(short)f2b(x0.x); v[1]=(short)f2b(x0.y); v[2]=(short)f2b(x0.z); v[3]=(short)f2b(x0.w);
        v[4]=(short)f2b(x1.x); v[5]=(short)f2b(x1.y); v[6]=(short)f2b(x1.z); v[7]=(short)f2b(x1.w);
        *(bf16x8*)(&kw[tid >> 3][(tid & 7) * 8]) = v;
    }
    {   // q
        const unsigned short* qp = YQ + (size_t)t * 4096 + g * 1024 + tid * 4;
        *(bf16x4*)(&sQ[tid >> 3][(tid & 7) * 4]) = *(const bf16x4*)qp;
    }
    if (tid < 32) sKB[tid] = kbp[g * 32 + tid];
    __syncthreads();

    // v = relu(LN2d(f @ vW)): wave = d-tile, mt = p-tile, K = 64.
    f32x4 accA[2] = {};
    #pragma unroll
    for (int ks = 0; ks < 64; ks += 32) {
        bf16x8 b = *(const bf16x8*)(&Vt[wave * 16 + l16][ks + quad * 8]);
        #pragma unroll
        for (int mt = 0; mt < 2; ++mt) {
            bf16x8 a = *(const bf16x8*)(&fB[mt * 16 + l16][ks + quad * 8]);
            accA[mt] = __builtin_amdgcn_mfma_f32_16x16x32_bf16(a, b, accA[mt], 0, 0, 0);
        }
    }
    float ls = 0.f, lq = 0.f;
    #pragma unroll
    for (int mt = 0; mt < 2; ++mt)
        #pragma unroll
        for (int r = 0; r < 4; ++r) { float v = accA[mt][r]; ls += v; lq += v * v; }
    float mean, istd;
    block_stats(ls, lq, sRed, tid, 1.0f / 2048.0f, mean, istd);
    {
        const int d = wave * 16 + l16;
        #pragma unroll
        for (int mt = 0; mt < 2; ++mt) {
            bf16x4 pk;
            #pragma unroll
            for (int r = 0; r < 4; ++r) {
                float y = (accA[mt][r] - mean) * istd;
                unsigned short u = f2b(y > 0.f ? y : 0.f);
                pk[r] = (short)u;
                vRM[mt * 16 + quad * 4 + r][d] = (short)u;   // row-major copy
            }
            *(bf16x4*)(&vT[d][mt * 16 + quad * 4]) = pk;     // transposed copy
        }
    }
    __syncthreads();

    // k[i][p] = kw[i][:]·v[p][:] + kb. 4 tiles: wave -> (it = w>>1, pt = w&1), K=64.
    {
        const int it = wave >> 1, pt = wave & 1;
        f32x4 accK = {};
        #pragma unroll
        for (int ks = 0; ks < 64; ks += 32) {
            bf16x8 a = *(const bf16x8*)(&kw[it * 16 + l16][ks + quad * 8]);
            bf16x8 b = *(const bf16x8*)(&vRM[pt * 16 + l16][ks + quad * 8]);
            accK = __builtin_amdgcn_mfma_f32_16x16x32_bf16(a, b, accK, 0, 0, 0);
        }
        bf16x4 pk;
        #pragma unroll
        for (int r = 0; r < 4; ++r)
            pk[r] = (short)f2b(accK[r] + sKB[it * 16 + quad * 4 + r]);
        // D: row i = it*16+quad*4+r, col p = pt*16+l16 -> kT[p][i]
        *(bf16x4*)(&kT[pt * 16 + l16][it * 16 + quad * 4]) = pk;
    }
    __syncthreads();

    // logits + softmax: waves 0,1 (wave = o-tile). K = 32 (i).
    if (wave < 2) {
        f32x4 accL[2] = {};
        bf16x8 a = *(const bf16x8*)(&sQ[wave * 16 + l16][quad * 8]);
        #pragma unroll
        for (int pt = 0; pt < 2; ++pt) {
            bf16x8 b = *(const bf16x8*)(&kT[pt * 16 + l16][quad * 8]);
            accL[pt] = __builtin_amdgcn_mfma_f32_16x16x32_bf16(a, b, accL[pt], 0, 0, 0);
        }
        #pragma unroll
        for (int r = 0; r < 4; ++r) {
            float a0 = accL[0][r] * 0.125f, a1 = accL[1][r] * 0.125f;
            float mx = fmaxf(a0, a1);
            #pragma unroll
            for (int m = 1; m < 16; m <<= 1) mx = fmaxf(mx, __shfl_xor(mx, m, 64));
            a0 = __expf(a0 - mx); a1 = __expf(a1 - mx);
            float sum = a0 + a1;
            #pragma unroll
            for (int m = 1; m < 16; m <<= 1) sum += __shfl_xor(sum, m, 64);
            const float inv_s = 1.0f / sum;
            const int o = wave * 16 + quad * 4 + r;
            sSC[o][l16]      = (short)f2b(a0 * inv_s);
            sSC[o][16 + l16] = (short)f2b(a1 * inv_s);
        }
    }
    __syncthreads();

    // fc = relu(LN2d(sc @ v)): wave = d-tile, K = 32 (p).
    f32x4 accB[2] = {};
    {
        bf16x8 b = *(const bf16x8*)(&vT[wave * 16 + l16][quad * 8]);
        #pragma unroll
        for (int mt = 0; mt < 2; ++mt) {
            bf16x8 a = *(const bf16x8*)(&sSC[mt * 16 + l16][quad * 8]);
            accB[mt] = __builtin_amdgcn_mfma_f32_16x16x32_bf16(a, b, accB[mt], 0, 0, 0);
        }
    }
    ls = 0.f; lq = 0.f;
    #pragma unroll
    for (int mt = 0; mt < 2; ++mt)
        #pragma unroll
        for (int r = 0; r < 4; ++r) { float v = accB[mt][r]; ls += v; lq += v * v; }
    block_stats(ls, lq, sRed, tid, 1.0f / 2048.0f, mean, istd);

    unsigned short* outp = FC + (size_t)t * 8192 + g * 2048;
    const int d = wave * 16 + l16;
    #pragma unroll
    for (int mt = 0; mt < 2; ++mt)
        #pragma unroll
        for (int r = 0; r < 4; ++r) {
            float y = (accB[mt][r] - mean) * istd;
            outp[(mt * 16 + quad * 4 + r) * 64 + d] = f2b(y > 0.f ? y : 0.f);
        }
}

// ---------------------------------------------------------------------------
// Final: reduce split-K partials, residual add, affine LN over 256, fp32 out.
// ---------------------------------------------------------------------------
__global__ __launch_bounds__(256) void final_ln_kernel(
    const float* __restrict__ qv,
    const float* __restrict__ MSP,   // (8, BN, 256) fp32 partials
    const float* __restrict__ CLP,
    const float* __restrict__ Wv_b,
    const float* __restrict__ Wv2_b,
    const float* __restrict__ lnA_w,
    const float* __restrict__ lnA_b,
    const float* __restrict__ lnB_w,
    const float* __restrict__ lnB_b,
    float* __restrict__ out)
{
    __shared__ float sRed[16];
    const int t = blockIdx.x;
    const int br = blockIdx.y;
    const int c = threadIdx.x;
    const float* P = br ? CLP : MSP;
    const float* bias = br ? Wv2_b : Wv_b;
    const float* lw = br ? lnB_w : lnA_w;
    const float* lb = br ? lnB_b : lnA_b;

    float x = qv[t * 256 + c] + bias[c];
    #pragma unroll
    for (int s = 0; s < 8; ++s) x += P[(size_t)s * (BN * 256) + t * 256 + c];

    float mean, istd;
    block_stats(x, x * x, sRed, c, 1.0f / 256.0f, mean, istd);
    out[(size_t)br * (BN * 256) + t * 256 + c] = (x - mean) * istd * lw[c] + lb[c];
}

// ---------------------------------------------------------------------------
extern "C" void kernel_launch(void* const* d_in, const int* in_sizes, int n_in,
                              void* d_out, int out_size, void* d_ws, size_t ws_size,
                              hipStream_t stream) {
    const float* feats = (const float*)d_in[0];
    const float* qv    = (const float*)d_in[1];
    const float* m_w   = (const float*)d_in[7];
    const float* m_b   = (const float*)d_in[8];
    const float* s_w   = (const float*)d_in[9];
    const float* s_b   = (const float*)d_in[10];
    const float* q_w   = (const float*)d_in[11];
    const float* q_b   = (const float*)d_in[12];
    const float* v_w   = (const float*)d_in[13];
    const float* v_b   = (const float*)d_in[14];
    const float* k_w   = (const float*)d_in[15];
    const float* k_b   = (const float*)d_in[16];
    const float* Wv_w  = (const float*)d_in[17];
    const float* Wv_b  = (const float*)d_in[18];
    const float* Wv2_w = (const float*)d_in[19];
    const float* Wv2_b = (const float*)d_in[20];
    const float* lnA_w = (const float*)d_in[21];
    const float* lnA_b = (const float*)d_in[22];
    const float* lnB_w = (const float*)d_in[23];
    const float* lnB_b = (const float*)d_in[24];

    char* ws = (char*)d_ws;
    // Workspace (177 MB peak), reuse schedule:
    //   preps -> [gen M,S] -> p2_reg -> [gen V,Q over YM/YS] -> p2_cls
    //   -> [MSP/CLP over YM] -> final.
    // Prepped weights live in the FC slot (dead until p2_cls writes FC).
    const size_t OFF_YM  = 0;                         // 78,643,200
    const size_t OFF_YS  = 78643200;                  // 19,660,800
    const size_t OFF_FMS = 98304000;                  // 39,321,600
    const size_t OFF_FC  = 137625600;                 // 39,321,600 (ends 176,947,200)
    const size_t OFF_MSP = 0;                         // 19,660,800 (YM dead)
    const size_t OFF_CLP = 19660800;

    unsigned short* YM  = (unsigned short*)(ws + OFF_YM);
    unsigned short* YS  = (unsigned short*)(ws + OFF_YS);
    unsigned short* FMS = (unsigned short*)(ws + OFF_FMS);
    unsigned short* FC  = (unsigned short*)(ws + OFF_FC);
    float* MSP = (float*)(ws + OFF_MSP);
    float* CLP = (float*)(ws + OFF_CLP);
    // prepped weights inside FC slot (21.1 MB <= 39.3 MB; all dead before p2_cls)
    unsigned short* m_wP = (unsigned short*)(ws + OFF_FC);
    unsigned short* v_wP = (unsigned short*)(ws + OFF_FC + 8388608);
    unsigned short* s_wB = (unsigned short*)(ws + OFF_FC + 16777216);
    unsigned short* q_wB = (unsigned short*)(ws + OFF_FC + 18874368);
    float* m_bP = (float*)(ws + OFF_FC + 20971520);
    float* v_bP = (float*)(ws + OFF_FC + 21037056);

    const dim3 blk(256);
    // weight prep: permute+cvt m_w/v_w (rows (g,c,d)->(g,d,c)), cvt s_w/q_w
    prep_w_kernel<1><<<4096, blk, 0, stream>>>(m_w, m_b, m_wP, m_bP);
    prep_w_kernel<1><<<4096, blk, 0, stream>>>(v_w, v_b, v_wP, v_bP);
    prep_w_kernel<0><<<1024, blk, 0, stream>>>(s_w, nullptr, s_wB, nullptr);
    prep_w_kernel<0><<<1024, blk, 0, stream>>>(q_w, nullptr, q_wB, nullptr);
    // reg branch
    gemm_nt_kernel<0,1,0><<<dim3(38, 256, 1), blk, 0, stream>>>(qv, m_wP, m_bP, YM, BN, 16384, 256, 256);
    gemm_nt_kernel<0,1,0><<<dim3(38, 64, 1),  blk, 0, stream>>>(qv, s_wB, s_b, YS, BN, 4096, 256, 256);
    p2_reg_kernel<<<dim3(BN, NG), blk, 0, stream>>>(feats, YM, YS, FMS);
    // cls branch (reuse YM/YS)
    gemm_nt_kernel<0,1,0><<<dim3(38, 256, 1), blk, 0, stream>>>(qv, v_wP, v_bP, YM, BN, 16384, 256, 256);
    gemm_nt_kernel<0,1,0><<<dim3(38, 64, 1),  blk, 0, stream>>>(qv, q_wB, q_b, YS, BN, 4096, 256, 256);
    p2_cls_kernel<<<dim3(BN, NG), blk, 0, stream>>>(feats, YM, YS, k_w, k_b, FC);
    // output projections: bf16 ws A, fp32 W, split-K=8 fp32 partials
    gemm_nt_kernel<2,0,1><<<dim3(38, 4, 8), blk, 0, stream>>>(FMS, Wv_w,  nullptr, MSP, BN, 256, 8192, 1024);
    gemm_nt_kernel<2,0,1><<<dim3(38, 4, 8), blk, 0, stream>>>(FC,  Wv2_w, nullptr, CLP, BN, 256, 8192, 1024);
    final_ln_kernel<<<dim3(BN, 2), blk, 0, stream>>>(qv, MSP, CLP, Wv_b, Wv2_b,
                                                     lnA_w, lnA_b, lnB_w, lnB_b,
                                                     (float*)d_out);
}